// Round 2
// baseline (198.253 us; speedup 1.0000x reference)
//
#include <hip/hip_runtime.h>
#include <hip/hip_fp16.h>

#define IRR    56
#define EF     48
#define WN     832
#define NEDGE  160000
#define NNODE  8000
#define NT     256
#define TE2    64                 // edges per block (one task per block)
#define NTASK  (NEDGE / TE2)      // 2500
#define GRID   (2 * NTASK)        // 5000: 2 flavors x 2500 tasks

#define INV_SQRT3 0.5773502691896258f
#define INV_SQRT2 0.7071067811865476f
#define A_SCAL    0.22360679774997896f   // 1/sqrt(20)
#define A_VEC     0.20412414523193154f   // 1/sqrt(24)

typedef __bf16 bf16x8 __attribute__((ext_vector_type(8)));
typedef float  f32x4  __attribute__((ext_vector_type(4)));
typedef unsigned short u16x8 __attribute__((ext_vector_type(8)));
typedef unsigned short u16x4 __attribute__((ext_vector_type(4)));

__device__ __forceinline__ unsigned short f2bf(float f) {
    unsigned int u = __builtin_bit_cast(unsigned int, f);
    u += 0x7FFFu + ((u >> 16) & 1u);          // RNE
    return (unsigned short)(u >> 16);
}

// ---- setup: W1T [n][64] + W2L lane-major fragment layout + src histogram ----
// W2L[o]: o = ((i*2+f)*64 + l)*8 + j ; lane l=(q*16+m); value = W2[k= f*32+q*8+j][n= i*16+m]
__global__ void k_setup(const float* __restrict__ w1, const float* __restrict__ b1,
                        const float* __restrict__ w2, const float* __restrict__ b2,
                        unsigned short* __restrict__ W1T, unsigned short* __restrict__ W2L,
                        const int* __restrict__ edge_index, int* __restrict__ hist)
{
    int o = blockIdx.x * 256 + threadIdx.x;
    if (o < 52 * 2 * 64 * 8) {
        int i = o >> 10;
        int rem = o & 1023;
        int f = rem >> 9;
        int rem2 = rem & 511;
        int l = rem2 >> 3, j = rem2 & 7;
        int mm = l & 15, qq = l >> 4;
        int k = f * 32 + qq * 8 + j;
        int n = i * 16 + mm;
        float v = (k < EF) ? w2[k * WN + n] : ((k == EF) ? b2[n] : 0.f);
        W2L[o] = f2bf(v);
    }
    if (o < EF * EF) { int k = o / EF, n = o - k * EF; W1T[n * 64 + k] = f2bf(w1[o]); }
    if (o < EF * 16) { int n = o >> 4, kk = EF + (o & 15); W1T[n * 64 + kk] = (kk == EF) ? f2bf(b1[n]) : (unsigned short)0; }
    if (o < NEDGE) atomicAdd(&hist[edge_index[o]], 1);   // src counts
}

// ---- exclusive prefix sum of hist[8000] -> offs (single block) ----
__global__ __launch_bounds__(256) void k_scan(const int* __restrict__ hist, int* __restrict__ offs)
{
    __shared__ int part[256];
    int t = threadIdx.x;
    int s = 0;
    #pragma unroll
    for (int j = 0; j < 32; j++) { int i = t * 32 + j; s += (i < NNODE) ? hist[i] : 0; }
    part[t] = s;
    __syncthreads();
    for (int d = 1; d < 256; d <<= 1) {
        int v = (t >= d) ? part[t - d] : 0;
        __syncthreads();
        part[t] += v;
        __syncthreads();
    }
    int run = (t > 0) ? part[t - 1] : 0;
    #pragma unroll
    for (int j = 0; j < 32; j++) {
        int i = t * 32 + j;
        if (i < NNODE) { offs[i] = run; run += hist[i]; }
    }
}

// ---- slot assignment: slot[e] = offs[src] + rank (int atomics, cheap) ----
__global__ __launch_bounds__(256) void k_slot(const int* __restrict__ edge_index,
                                              const int* __restrict__ offs,
                                              int* __restrict__ cursor,
                                              int* __restrict__ slot)
{
    int e = blockIdx.x * 256 + threadIdx.x;
    if (e < NEDGE) {
        int s = edge_index[e];
        slot[e] = offs[s] + atomicAdd(&cursor[s], 1);
    }
}

// ---- per-node reduction over contiguous tpbuf rows (no atomics) ----
__global__ __launch_bounds__(256) void k_reduce(const float* __restrict__ tpbuf,
                                                const int* __restrict__ offs,
                                                const int* __restrict__ hist,
                                                float* __restrict__ out)
{
    int node = blockIdx.x * 4 + (threadIdx.x >> 6);
    int lane = threadIdx.x & 63;
    if (node >= NNODE || lane >= IRR) return;
    int base = offs[node], cnt = hist[node];
    const float* p = tpbuf + (size_t)base * IRR + lane;
    float a0 = 0.f, a1 = 0.f, a2 = 0.f, a3 = 0.f;
    int r = 0;
    for (; r + 4 <= cnt; r += 4) {
        a0 += p[0]; a1 += p[IRR]; a2 += p[2 * IRR]; a3 += p[3 * IRR];
        p += 4 * IRR;
    }
    for (; r < cnt; ++r) { a0 += p[0]; p += IRR; }
    float s = (a0 + a1) + (a2 + a3);
    out[(size_t)node * IRR + lane] = s / fmaxf((float)cnt, 1.0f);
}

__global__ __launch_bounds__(NT, 4) void tp_fused(
    const float* __restrict__ node_attr,
    const float* __restrict__ edge_attr,
    const float* __restrict__ edge_sh,
    const int*   __restrict__ edge_index,
    const int*   __restrict__ hist,
    const unsigned short* __restrict__ W1T,
    const unsigned short* __restrict__ W2L,
    const int*   __restrict__ slot,
    float* __restrict__ tpbuf,          // CSR mode if non-null
    float* __restrict__ out)            // fallback atomic mode target
{
    __shared__ __align__(16) unsigned char UGH[TE2 * 56 * 4];  // 14336 B: sG f32 s56 -> sH u16 s72 overlay
    __shared__ __align__(16) float sF[TE2 * 61];               // 15616 B
    __shared__ __align__(16) float sO[TE2 * 28];               // 7168 B
    __shared__ int   sSrc[TE2], sDst[TE2], sSlot[TE2];
    __shared__ float sInv[TE2];

    float*          sG = (float*)UGH;            // stride 56 f32
    unsigned short* sH = (unsigned short*)UGH;   // stride 72 u16

    const int tid    = threadIdx.x;
    const int lane   = tid & 63;
    const int wv     = tid >> 6;
    const int m      = lane & 15;
    const int quad   = lane >> 4;
    const int em     = wv * 16 + m;              // block-local edge owned by this lane
    const int flavor = blockIdx.x & 1;           // 0: ch 0..27 ; 1: ch 28..55
    const int e0     = (blockIdx.x >> 1) * TE2;
    const bool csr   = (tpbuf != nullptr);

    if (tid < TE2)                 sSrc[tid]        = edge_index[e0 + tid];
    else if (tid < 2 * TE2)        sDst[tid - TE2]  = edge_index[NEDGE + e0 + tid - TE2];
    else if (csr && tid < 3 * TE2) sSlot[tid - 2 * TE2] = slot[e0 + tid - 2 * TE2];
    __syncthreads();   // (A) sSrc/sDst/sSlot visible

    // ---- gather node rows (wave-local rows of sG) ----
    {
        const float* nrow = node_attr + (size_t)sDst[em] * IRR;
        float* g = sG + em * 56;
        #pragma unroll
        for (int t = 0; t < 3; t++) {
            int c = quad + t * 4;
            *(float4*)(g + c * 4) = *(const float4*)(nrow + c * 4);
        }
        if (quad < 2) { int c = 12 + quad; *(float4*)(g + c * 4) = *(const float4*)(nrow + c * 4); }
    }
    if (!csr && tid >= 128 && tid < 128 + TE2) {
        int e = tid - 128;
        sInv[e] = 1.0f / fmaxf((float)hist[sSrc[e]], 1.0f);
    }

    // edge_sh kept in registers
    float4 sh4 = *(const float4*)&edge_sh[(size_t)(e0 + em) * 4];
    const float s0 = sh4.x, sx = sh4.y, sy = sh4.z, sz = sh4.w;

    // ---- F features in f32, parallelized across all 4 quads (wave-local: DS in-order) ----
    {
        const float* x = sG + em * 56;
        float* F = sF + em * 61;
        const float c0S = s0 * A_SCAL;
        const float c0V = s0 * A_VEC;
        const float cD3 = INV_SQRT3 * A_SCAL;
        const float cC2 = INV_SQRT2 * A_VEC;
        if (flavor == 0) {
            #pragma unroll
            for (int t = 0; t < 4; t++) {
                int u = quad * 4 + t;
                float x0e = x[u];
                F[u]      = x0e * c0S;    // wA0
                F[20 + u] = x0e * A_VEC;  // wA1
            }
            {
                int u = quad;
                float a0 = x[16 + u*3], a1 = x[16 + u*3 + 1], a2 = x[16 + u*3 + 2]; // x1o
                float b0 = x[28 + u*3], b1 = x[28 + u*3 + 1], b2 = x[28 + u*3 + 2]; // x1e
                F[16 + u] = (a0*sx + a1*sy + a2*sz) * cD3;        // wB0 dot_b
                F[36 + u*3 + 0] = a0 * c0V;                       // wB1
                F[36 + u*3 + 1] = a1 * c0V;
                F[36 + u*3 + 2] = a2 * c0V;
                F[48 + u*3 + 0] = (b1*sz - b2*sy) * cC2;          // wC1 cross(x1e,s1)
                F[48 + u*3 + 1] = (b2*sx - b0*sz) * cC2;
                F[48 + u*3 + 2] = (b0*sy - b1*sx) * cC2;
            }
        } else {
            {
                int u = quad;
                float a0 = x[16 + u*3], a1 = x[16 + u*3 + 1], a2 = x[16 + u*3 + 2]; // x1o
                float b0 = x[28 + u*3], b1 = x[28 + u*3 + 1], b2 = x[28 + u*3 + 2]; // x1e
                F[u*3 + 0]      = (a1*sz - a2*sy) * cC2;          // wB1e cross(x1o,s1)
                F[u*3 + 1]      = (a2*sx - a0*sz) * cC2;
                F[u*3 + 2]      = (a0*sy - a1*sx) * cC2;
                F[12 + u*3 + 0] = b0 * c0V;                       // wC1e
                F[12 + u*3 + 1] = b1 * c0V;
                F[12 + u*3 + 2] = b2 * c0V;
                F[40 + u]       = (b0*sx + b1*sy + b2*sz) * cD3;  // wC0o dot_c
            }
            #pragma unroll
            for (int t = 0; t < 4; t++) {
                int u = quad * 4 + t;
                float x0o = x[40 + u];
                F[24 + u] = x0o * A_VEC;  // wD1e
                F[44 + u] = x0o * c0S;    // wD0o
            }
        }
    }

    // ---- preload edge_attr -> bf16 regs BEFORE barrier (global latency hides under F) ----
    bf16x8 hb0, hb1;
    {
        const float* arow = edge_attr + (size_t)(e0 + em) * EF;
        float av0[8], av1[8];
        {
            float4 p0 = *(const float4*)(arow + quad * 8);
            float4 p1 = *(const float4*)(arow + quad * 8 + 4);
            av0[0]=p0.x; av0[1]=p0.y; av0[2]=p0.z; av0[3]=p0.w;
            av0[4]=p1.x; av0[5]=p1.y; av0[6]=p1.z; av0[7]=p1.w;
        }
        if (quad < 2) {
            float4 p0 = *(const float4*)(arow + 32 + quad * 8);
            float4 p1 = *(const float4*)(arow + 32 + quad * 8 + 4);
            av1[0]=p0.x; av1[1]=p0.y; av1[2]=p0.z; av1[3]=p0.w;
            av1[4]=p1.x; av1[5]=p1.y; av1[6]=p1.z; av1[7]=p1.w;
        } else {
            #pragma unroll
            for (int j = 0; j < 8; j++) av1[j] = 0.f;
            if (quad == 2) av1[0] = 1.f;           // bias row k=48
        }
        u16x8 ub0, ub1;
        #pragma unroll
        for (int j = 0; j < 8; j++) { ub0[j] = f2bf(av0[j]); ub1[j] = f2bf(av1[j]); }
        hb0 = __builtin_bit_cast(bf16x8, ub0);
        hb1 = __builtin_bit_cast(bf16x8, ub1);
    }

    __syncthreads();   // (B) all sG reads done block-wide -> sH may overlay

    // ---- GEMM1: lane holds H[e=em][hid] -> sH (wave-local rows) ----
    #pragma unroll
    for (int nth = 0; nth < 3; nth++) {
        bf16x8 a0 = __builtin_bit_cast(bf16x8, *(const u16x8*)&W1T[(nth*16 + m)*64 + quad*8]);
        bf16x8 a1 = __builtin_bit_cast(bf16x8, *(const u16x8*)&W1T[(nth*16 + m)*64 + 32 + quad*8]);
        f32x4 c = {0.f, 0.f, 0.f, 0.f};
        c = __builtin_amdgcn_mfma_f32_16x16x32_bf16(a0, hb0, c, 0, 0, 0);
        c = __builtin_amdgcn_mfma_f32_16x16x32_bf16(a1, hb1, c, 0, 0, 0);
        u16x4 hp;
        #pragma unroll
        for (int r = 0; r < 4; r++) hp[r] = f2bf(fmaxf(c[r], 0.f));
        *(u16x4*)&sH[em * 72 + nth*16 + quad*4] = hp;
    }
    if (quad == 3) {
        u16x4 b = {0x3F80, 0, 0, 0}, z = {0, 0, 0, 0};
        *(u16x4*)&sH[em * 72 + 48] = b;
        *(u16x4*)&sH[em * 72 + 52] = z;
        *(u16x4*)&sH[em * 72 + 56] = z;
        *(u16x4*)&sH[em * 72 + 60] = z;
    }
    // no barrier: sH rows em are wave-local; DS ops are in-order per wave

    bf16x8 HB0 = __builtin_bit_cast(bf16x8, *(const u16x8*)&sH[em * 72 + quad*8]);
    bf16x8 HB1 = __builtin_bit_cast(bf16x8, *(const u16x8*)&sH[em * 72 + 32 + quad*8]);

    const float* Fp = sF + em * 61;
    const unsigned short* Wt = W2L + (size_t)flavor * 26 * 1024;  // global, L2-hot

    if (flavor == 0) {
        // ---- tiles 0..25: o0e (ch 0..15) + o1o (ch 16..27) ----
        float oe[4] = {0.f,0.f,0.f,0.f};
        float sA[4] = {0.f,0.f,0.f,0.f};
        float t1[12] = {0.f,0.f,0.f,0.f,0.f,0.f,0.f,0.f,0.f,0.f,0.f,0.f};
        #pragma unroll
        for (int i = 0; i < 26; i++) {
            u16x8 Af = *(const u16x8*)&Wt[i * 1024 + lane * 8];
            u16x8 Bf = *(const u16x8*)&Wt[i * 1024 + 512 + lane * 8];
            f32x4 c = {0.f,0.f,0.f,0.f};
            c = __builtin_amdgcn_mfma_f32_16x16x32_bf16(__builtin_bit_cast(bf16x8, Af), HB0, c, 0, 0, 0);
            c = __builtin_amdgcn_mfma_f32_16x16x32_bf16(__builtin_bit_cast(bf16x8, Bf), HB1, c, 0, 0, 0);
            if (i < 20) {
                float f = Fp[i];
                #pragma unroll
                for (int r = 0; r < 4; r++) oe[r] += f * c[r];
            } else if (i < 24) {
                float f = Fp[20 + (i - 20)*4 + quad];
                #pragma unroll
                for (int r = 0; r < 4; r++) sA[r] += f * c[r];
            } else {
                int u = (i - 24)*4 + quad;
                #pragma unroll
                for (int i3 = 0; i3 < 3; i3++) {
                    float f = Fp[36 + u*3 + i3];
                    #pragma unroll
                    for (int r = 0; r < 4; r++) t1[i3*4 + r] += f * c[r];
                }
            }
        }
        #pragma unroll
        for (int r = 0; r < 4; r++) {
            sA[r] += __shfl_xor(sA[r], 16, 64);  sA[r] += __shfl_xor(sA[r], 32, 64);
        }
        #pragma unroll
        for (int i = 0; i < 12; i++) {
            t1[i] += __shfl_xor(t1[i], 16, 64);  t1[i] += __shfl_xor(t1[i], 32, 64);
        }
        float4 v0; v0.x = oe[0]; v0.y = oe[1]; v0.z = oe[2]; v0.w = oe[3];
        *(float4*)&sO[em * 28 + quad*4] = v0;                 // ch 0..15
        if (quad == 0) {
            #pragma unroll
            for (int r = 0; r < 4; r++) {
                sO[em * 28 + 16 + r*3 + 0] = sA[r] * sx + t1[0*4 + r];
                sO[em * 28 + 16 + r*3 + 1] = sA[r] * sy + t1[1*4 + r];
                sO[em * 28 + 16 + r*3 + 2] = sA[r] * sz + t1[2*4 + r];
            }
        }
    } else {
        // ---- tiles 26..51: o1e (ch 28..39) + o0o (ch 40..55) ----
        float sD[4] = {0.f,0.f,0.f,0.f};
        float t1[12] = {0.f,0.f,0.f,0.f,0.f,0.f,0.f,0.f,0.f,0.f,0.f,0.f};
        float oo[4] = {0.f,0.f,0.f,0.f};
        #pragma unroll
        for (int i = 0; i < 26; i++) {
            u16x8 Af = *(const u16x8*)&Wt[i * 1024 + lane * 8];
            u16x8 Bf = *(const u16x8*)&Wt[i * 1024 + 512 + lane * 8];
            f32x4 c = {0.f,0.f,0.f,0.f};
            c = __builtin_amdgcn_mfma_f32_16x16x32_bf16(__builtin_bit_cast(bf16x8, Af), HB0, c, 0, 0, 0);
            c = __builtin_amdgcn_mfma_f32_16x16x32_bf16(__builtin_bit_cast(bf16x8, Bf), HB1, c, 0, 0, 0);
            if (i < 2) {
                int j = i*4 + quad;
                #pragma unroll
                for (int i3 = 0; i3 < 3; i3++) {
                    float f = Fp[j*3 + i3];
                    #pragma unroll
                    for (int r = 0; r < 4; r++) t1[i3*4 + r] += f * c[r];
                }
            } else if (i < 6) {
                float f = Fp[24 + (i - 2)*4 + quad];
                #pragma unroll
                for (int r = 0; r < 4; r++) sD[r] += f * c[r];
            } else {
                float f = Fp[40 + (i - 6)];
                #pragma unroll
                for (int r = 0; r < 4; r++) oo[r] += f * c[r];
            }
        }
        #pragma unroll
        for (int r = 0; r < 4; r++) {
            sD[r] += __shfl_xor(sD[r], 16, 64);  sD[r] += __shfl_xor(sD[r], 32, 64);
        }
        #pragma unroll
        for (int i = 0; i < 12; i++) {
            t1[i] += __shfl_xor(t1[i], 16, 64);  t1[i] += __shfl_xor(t1[i], 32, 64);
        }
        float4 v1; v1.x = oo[0]; v1.y = oo[1]; v1.z = oo[2]; v1.w = oo[3];
        *(float4*)&sO[em * 28 + 12 + quad*4] = v1;            // local ch 12..27 -> global 40..55
        if (quad == 0) {
            #pragma unroll
            for (int r = 0; r < 4; r++) {                     // local ch 0..11 -> global 28..39
                sO[em * 28 + r*3 + 0] = sD[r] * sx + t1[0*4 + r];
                sO[em * 28 + r*3 + 1] = sD[r] * sy + t1[1*4 + r];
                sO[em * 28 + r*3 + 2] = sD[r] * sz + t1[2*4 + r];
            }
        }
    }

    __syncthreads();   // (C) sO complete block-wide

    if (csr) {
        // ---- plain stores to CSR-ordered tpbuf rows (no atomics) ----
        #pragma unroll
        for (int it = 0; it < 7; it++) {
            int idx = it * NT + tid;           // < 1792 = 64*28
            int e = idx / 28, ch = idx - e * 28;
            tpbuf[(size_t)sSlot[e] * IRR + flavor * 28 + ch] = sO[e * 28 + ch];
        }
    } else {
        // ---- fallback: pre-scaled channel-major atomic scatter ----
        #pragma unroll
        for (int it = 0; it < 7; it++) {
            int idx = it * NT + tid;
            int e = idx / 28, ch = idx - e * 28;
            unsafeAtomicAdd(&out[(size_t)sSrc[e] * IRR + flavor * 28 + ch],
                            sO[e * 28 + ch] * sInv[e]);
        }
    }
}

extern "C" void kernel_launch(void* const* d_in, const int* in_sizes, int n_in,
                              void* d_out, int out_size, void* d_ws, size_t ws_size,
                              hipStream_t stream) {
    const float* node_attr  = (const float*)d_in[0];
    const float* edge_attr  = (const float*)d_in[1];
    const float* edge_sh    = (const float*)d_in[2];
    const float* fc_w1      = (const float*)d_in[3];
    const float* fc_b1      = (const float*)d_in[4];
    const float* fc_w2      = (const float*)d_in[5];
    const float* fc_b2      = (const float*)d_in[6];
    const int*   edge_index = (const int*)d_in[7];

    // workspace layout
    int* hist   = (int*)d_ws;                                  // 8000 ints
    int* cursor = hist + NNODE;                                // 8000 ints
    int* offs   = cursor + NNODE;                              // 8000 ints
    unsigned short* W1T = (unsigned short*)(offs + NNODE);     // 48*64   = 3072 u16
    unsigned short* W2L = W1T + EF * 64;                       // 53248 u16
    int*   slot  = (int*)(W2L + 52 * 2 * 64 * 8);              // 160000 ints
    float* tpbuf = (float*)(slot + NEDGE);                     // 160000*56 f32 = 35.84 MB

    size_t need = (size_t)((char*)(tpbuf + (size_t)NEDGE * IRR) - (char*)d_ws);
    bool csr = (ws_size >= need);

    if (csr) {
        hipMemsetAsync(hist, 0, 2 * NNODE * sizeof(int), stream);   // hist + cursor
        k_setup<<<(NEDGE + 255) / 256, 256, 0, stream>>>(
            fc_w1, fc_b1, fc_w2, fc_b2, W1T, W2L, edge_index, hist);
        k_scan<<<1, 256, 0, stream>>>(hist, offs);
        k_slot<<<(NEDGE + 255) / 256, 256, 0, stream>>>(edge_index, offs, cursor, slot);
        tp_fused<<<GRID, NT, 0, stream>>>(node_attr, edge_attr, edge_sh, edge_index,
                                          hist, W1T, W2L, slot, tpbuf, (float*)d_out);
        k_reduce<<<(NNODE + 3) / 4, 256, 0, stream>>>(tpbuf, offs, hist, (float*)d_out);
    } else {
        hipMemsetAsync(hist, 0, NNODE * sizeof(int), stream);
        hipMemsetAsync(d_out, 0, (size_t)out_size * sizeof(float), stream);
        k_setup<<<(NEDGE + 255) / 256, 256, 0, stream>>>(
            fc_w1, fc_b1, fc_w2, fc_b2, W1T, W2L, edge_index, hist);
        tp_fused<<<GRID, NT, 0, stream>>>(node_attr, edge_attr, edge_sh, edge_index,
                                          hist, W1T, W2L, nullptr, nullptr, (float*)d_out);
    }
}

// Round 3
// 168.685 us; speedup vs baseline: 1.1753x; 1.1753x over previous
//
#include <hip/hip_runtime.h>
#include <hip/hip_fp16.h>

#define IRR    56
#define EF     48
#define WN     832
#define NEDGE  160000
#define NNODE  8000
#define NT     512                // 8 waves: crew0 (waves 0-3) flavor 0, crew1 (waves 4-7) flavor 1
#define TE2    64                 // edges per block
#define NTASK  (NEDGE / TE2)      // 2500
#define GRID   NTASK              // flavors merged -> one block per 64 edges

#define INV_SQRT3 0.5773502691896258f
#define INV_SQRT2 0.7071067811865476f
#define A_SCAL    0.22360679774997896f   // 1/sqrt(20)
#define A_VEC     0.20412414523193154f   // 1/sqrt(24)

typedef __bf16 bf16x8 __attribute__((ext_vector_type(8)));
typedef float  f32x4  __attribute__((ext_vector_type(4)));
typedef unsigned short u16x8 __attribute__((ext_vector_type(8)));
typedef unsigned short u16x4 __attribute__((ext_vector_type(4)));

__device__ __forceinline__ unsigned short f2bf(float f) {
    unsigned int u = __builtin_bit_cast(unsigned int, f);
    u += 0x7FFFu + ((u >> 16) & 1u);          // RNE
    return (unsigned short)(u >> 16);
}

// ---- setup: W1T [n][64] + W2L lane-major fragment layout + src histogram ----
// W2L[o]: o = ((i*2+f)*64 + l)*8 + j ; lane l=(q*16+m); value = W2[k= f*32+q*8+j][n= i*16+m]
// Rewritten source-major: thread e -> (k = e/832, n = e%832) so w2 reads are coalesced.
__global__ void k_setup(const float* __restrict__ w1, const float* __restrict__ b1,
                        const float* __restrict__ w2, const float* __restrict__ b2,
                        unsigned short* __restrict__ W1T, unsigned short* __restrict__ W2L,
                        const int* __restrict__ edge_index, int* __restrict__ hist)
{
    int o = blockIdx.x * 256 + threadIdx.x;
    if (o < 64 * 832) {                       // 53248 elements, coalesced over n
        int k = o / 832;                      // magic-mul
        int n = o - k * 832;
        float v = (k < EF) ? w2[k * WN + n] : ((k == EF) ? b2[n] : 0.f);
        int i = n >> 4, mm = n & 15;
        int f = k >> 5, q = (k >> 3) & 3, j = k & 7;
        int o2 = (((i * 2 + f) * 64) + (q * 16 + mm)) * 8 + j;
        W2L[o2] = f2bf(v);
    }
    if (o < EF * EF) { int k = o / EF, n = o - k * EF; W1T[n * 64 + k] = f2bf(w1[o]); }
    if (o < EF * 16) { int n = o >> 4, kk = EF + (o & 15); W1T[n * 64 + kk] = (kk == EF) ? f2bf(b1[n]) : (unsigned short)0; }
    if (o < NEDGE) atomicAdd(&hist[edge_index[o]], 1);   // src counts
}

__global__ __launch_bounds__(NT, 4) void tp_fused(
    const float* __restrict__ node_attr,
    const float* __restrict__ edge_attr,
    const float* __restrict__ edge_sh,
    const int*   __restrict__ edge_index,
    const int*   __restrict__ hist,
    const unsigned short* __restrict__ W1T,
    const unsigned short* __restrict__ W2L,
    float* __restrict__ out)
{
    // LDS ~60.7 KB -> 2 blocks/CU = 16 waves/CU (same waves as round 1, half the blocks/work).
    __shared__ __align__(16) unsigned char UGH[TE2 * 56 * 4];  // 14336 B: sG f32 s56 -> sH u16 s72 overlay
    __shared__ __align__(16) float sF0[TE2 * 61];              // 15616 B flavor-0 features
    __shared__ __align__(16) float sF1[TE2 * 61];              // 15616 B flavor-1 features
    __shared__ __align__(16) float sO[TE2 * IRR];              // 14336 B full 56-ch rows
    __shared__ int   sSrc[TE2], sDst[TE2];
    __shared__ float sInv[TE2];

    float*          sG = (float*)UGH;            // stride 56 f32
    unsigned short* sH = (unsigned short*)UGH;   // stride 72 u16

    const int tid   = threadIdx.x;
    const int lane  = tid & 63;
    const int wv    = tid >> 6;                  // 0..7
    const int half  = wv >> 2;                   // crew: 0 -> flavor 0, 1 -> flavor 1
    const int wl    = wv & 3;                    // wave within crew
    const int m     = lane & 15;
    const int quad  = lane >> 4;
    const int em    = wl * 16 + m;               // block-local edge owned by this lane (per crew)
    const int e0    = blockIdx.x * TE2;

    if (tid < TE2)          sSrc[tid]       = edge_index[e0 + tid];
    else if (tid < 2 * TE2) sDst[tid - TE2] = edge_index[NEDGE + e0 + tid - TE2];
    __syncthreads();   // (A) sSrc/sDst visible

    // ---- gather node rows: split across all 8 waves (crew0 cols 0-7, crew1 cols 8-13) ----
    {
        const float* nrow = node_attr + (size_t)sDst[em] * IRR;
        float* g = sG + em * 56;
        if (half == 0) {
            *(float4*)(g + quad * 4)        = *(const float4*)(nrow + quad * 4);
            *(float4*)(g + (quad + 4) * 4)  = *(const float4*)(nrow + (quad + 4) * 4);
        } else {
            *(float4*)(g + (quad + 8) * 4)  = *(const float4*)(nrow + (quad + 8) * 4);
            if (quad < 2) { int c = 12 + quad; *(float4*)(g + c * 4) = *(const float4*)(nrow + c * 4); }
        }
    }
    if (tid >= 256 && tid < 256 + TE2) {         // wave 4 computes inv counts
        int e = tid - 256;
        sInv[e] = 1.0f / fmaxf((float)hist[sSrc[e]], 1.0f);
    }

    // edge_sh kept in registers (each lane holds its em's values)
    float4 sh4 = *(const float4*)&edge_sh[(size_t)(e0 + em) * 4];
    const float s0 = sh4.x, sx = sh4.y, sy = sh4.z, sz = sh4.w;

    __syncthreads();   // (B) sG complete

    // ---- F features in f32: crew0 builds F0, crew1 builds F1 (wave-local rows) ----
    {
        const float* x = sG + em * 56;
        const float c0S = s0 * A_SCAL;
        const float c0V = s0 * A_VEC;
        const float cD3 = INV_SQRT3 * A_SCAL;
        const float cC2 = INV_SQRT2 * A_VEC;
        if (half == 0) {
            float* F = sF0 + em * 61;
            #pragma unroll
            for (int t = 0; t < 4; t++) {
                int u = quad * 4 + t;
                float x0e = x[u];
                F[u]      = x0e * c0S;    // wA0
                F[20 + u] = x0e * A_VEC;  // wA1
            }
            {
                int u = quad;
                float a0 = x[16 + u*3], a1 = x[16 + u*3 + 1], a2 = x[16 + u*3 + 2]; // x1o
                float b0 = x[28 + u*3], b1 = x[28 + u*3 + 1], b2 = x[28 + u*3 + 2]; // x1e
                F[16 + u] = (a0*sx + a1*sy + a2*sz) * cD3;        // wB0 dot_b
                F[36 + u*3 + 0] = a0 * c0V;                       // wB1
                F[36 + u*3 + 1] = a1 * c0V;
                F[36 + u*3 + 2] = a2 * c0V;
                F[48 + u*3 + 0] = (b1*sz - b2*sy) * cC2;          // wC1 cross(x1e,s1)
                F[48 + u*3 + 1] = (b2*sx - b0*sz) * cC2;
                F[48 + u*3 + 2] = (b0*sy - b1*sx) * cC2;
            }
        } else {
            float* F = sF1 + em * 61;
            {
                int u = quad;
                float a0 = x[16 + u*3], a1 = x[16 + u*3 + 1], a2 = x[16 + u*3 + 2]; // x1o
                float b0 = x[28 + u*3], b1 = x[28 + u*3 + 1], b2 = x[28 + u*3 + 2]; // x1e
                F[u*3 + 0]      = (a1*sz - a2*sy) * cC2;          // wB1e cross(x1o,s1)
                F[u*3 + 1]      = (a2*sx - a0*sz) * cC2;
                F[u*3 + 2]      = (a0*sy - a1*sx) * cC2;
                F[12 + u*3 + 0] = b0 * c0V;                       // wC1e
                F[12 + u*3 + 1] = b1 * c0V;
                F[12 + u*3 + 2] = b2 * c0V;
                F[40 + u]       = (b0*sx + b1*sy + b2*sz) * cD3;  // wC0o dot_c
            }
            #pragma unroll
            for (int t = 0; t < 4; t++) {
                int u = quad * 4 + t;
                float x0o = x[40 + u];
                F[24 + u] = x0o * A_VEC;  // wD1e
                F[44 + u] = x0o * c0S;    // wD0o
            }
        }
    }

    // ---- crew0 preloads edge_attr -> bf16 regs (latency hides under F build) ----
    bf16x8 hb0, hb1;
    if (half == 0) {
        const float* arow = edge_attr + (size_t)(e0 + em) * EF;
        float av0[8], av1[8];
        {
            float4 p0 = *(const float4*)(arow + quad * 8);
            float4 p1 = *(const float4*)(arow + quad * 8 + 4);
            av0[0]=p0.x; av0[1]=p0.y; av0[2]=p0.z; av0[3]=p0.w;
            av0[4]=p1.x; av0[5]=p1.y; av0[6]=p1.z; av0[7]=p1.w;
        }
        if (quad < 2) {
            float4 p0 = *(const float4*)(arow + 32 + quad * 8);
            float4 p1 = *(const float4*)(arow + 32 + quad * 8 + 4);
            av1[0]=p0.x; av1[1]=p0.y; av1[2]=p0.z; av1[3]=p0.w;
            av1[4]=p1.x; av1[5]=p1.y; av1[6]=p1.z; av1[7]=p1.w;
        } else {
            #pragma unroll
            for (int j = 0; j < 8; j++) av1[j] = 0.f;
            if (quad == 2) av1[0] = 1.f;           // bias row k=48
        }
        u16x8 ub0, ub1;
        #pragma unroll
        for (int j = 0; j < 8; j++) { ub0[j] = f2bf(av0[j]); ub1[j] = f2bf(av1[j]); }
        hb0 = __builtin_bit_cast(bf16x8, ub0);
        hb1 = __builtin_bit_cast(bf16x8, ub1);
    }

    __syncthreads();   // (C) all sG reads done (both crews' F builds) -> sH may overlay

    // ---- GEMM1 (crew0 only): H[e][hid] -> sH ----
    if (half == 0) {
        #pragma unroll
        for (int nth = 0; nth < 3; nth++) {
            bf16x8 a0 = __builtin_bit_cast(bf16x8, *(const u16x8*)&W1T[(nth*16 + m)*64 + quad*8]);
            bf16x8 a1 = __builtin_bit_cast(bf16x8, *(const u16x8*)&W1T[(nth*16 + m)*64 + 32 + quad*8]);
            f32x4 c = {0.f, 0.f, 0.f, 0.f};
            c = __builtin_amdgcn_mfma_f32_16x16x32_bf16(a0, hb0, c, 0, 0, 0);
            c = __builtin_amdgcn_mfma_f32_16x16x32_bf16(a1, hb1, c, 0, 0, 0);
            u16x4 hp;
            #pragma unroll
            for (int r = 0; r < 4; r++) hp[r] = f2bf(fmaxf(c[r], 0.f));
            *(u16x4*)&sH[em * 72 + nth*16 + quad*4] = hp;
        }
        if (quad == 3) {
            u16x4 b = {0x3F80, 0, 0, 0}, z = {0, 0, 0, 0};
            *(u16x4*)&sH[em * 72 + 48] = b;
            *(u16x4*)&sH[em * 72 + 52] = z;
            *(u16x4*)&sH[em * 72 + 56] = z;
            *(u16x4*)&sH[em * 72 + 60] = z;
        }
    }
    __syncthreads();   // (D) sH visible to crew1

    bf16x8 HB0 = __builtin_bit_cast(bf16x8, *(const u16x8*)&sH[em * 72 + quad*8]);
    bf16x8 HB1 = __builtin_bit_cast(bf16x8, *(const u16x8*)&sH[em * 72 + 32 + quad*8]);

    const unsigned short* Wt = W2L + (size_t)half * 26 * 1024;  // global, L2-hot

    if (half == 0) {
        const float* Fp = sF0 + em * 61;
        // ---- tiles 0..25: o0e (ch 0..15) + o1o (ch 16..27) ----
        float oe[4] = {0.f,0.f,0.f,0.f};
        float sA[4] = {0.f,0.f,0.f,0.f};
        float t1[12] = {0.f,0.f,0.f,0.f,0.f,0.f,0.f,0.f,0.f,0.f,0.f,0.f};
        #pragma unroll
        for (int i = 0; i < 26; i++) {
            u16x8 Af = *(const u16x8*)&Wt[i * 1024 + lane * 8];
            u16x8 Bf = *(const u16x8*)&Wt[i * 1024 + 512 + lane * 8];
            f32x4 c = {0.f,0.f,0.f,0.f};
            c = __builtin_amdgcn_mfma_f32_16x16x32_bf16(__builtin_bit_cast(bf16x8, Af), HB0, c, 0, 0, 0);
            c = __builtin_amdgcn_mfma_f32_16x16x32_bf16(__builtin_bit_cast(bf16x8, Bf), HB1, c, 0, 0, 0);
            if (i < 20) {
                float f = Fp[i];
                #pragma unroll
                for (int r = 0; r < 4; r++) oe[r] += f * c[r];
            } else if (i < 24) {
                float f = Fp[20 + (i - 20)*4 + quad];
                #pragma unroll
                for (int r = 0; r < 4; r++) sA[r] += f * c[r];
            } else {
                int u = (i - 24)*4 + quad;
                #pragma unroll
                for (int i3 = 0; i3 < 3; i3++) {
                    float f = Fp[36 + u*3 + i3];
                    #pragma unroll
                    for (int r = 0; r < 4; r++) t1[i3*4 + r] += f * c[r];
                }
            }
        }
        #pragma unroll
        for (int r = 0; r < 4; r++) {
            sA[r] += __shfl_xor(sA[r], 16, 64);  sA[r] += __shfl_xor(sA[r], 32, 64);
        }
        #pragma unroll
        for (int i = 0; i < 12; i++) {
            t1[i] += __shfl_xor(t1[i], 16, 64);  t1[i] += __shfl_xor(t1[i], 32, 64);
        }
        float4 v0; v0.x = oe[0]; v0.y = oe[1]; v0.z = oe[2]; v0.w = oe[3];
        *(float4*)&sO[em * IRR + quad*4] = v0;                 // ch 0..15
        if (quad == 0) {
            #pragma unroll
            for (int r = 0; r < 4; r++) {
                sO[em * IRR + 16 + r*3 + 0] = sA[r] * sx + t1[0*4 + r];
                sO[em * IRR + 16 + r*3 + 1] = sA[r] * sy + t1[1*4 + r];
                sO[em * IRR + 16 + r*3 + 2] = sA[r] * sz + t1[2*4 + r];
            }
        }
    } else {
        const float* Fp = sF1 + em * 61;
        // ---- tiles 26..51: o1e (ch 28..39) + o0o (ch 40..55) ----
        float sD[4] = {0.f,0.f,0.f,0.f};
        float t1[12] = {0.f,0.f,0.f,0.f,0.f,0.f,0.f,0.f,0.f,0.f,0.f,0.f};
        float oo[4] = {0.f,0.f,0.f,0.f};
        #pragma unroll
        for (int i = 0; i < 26; i++) {
            u16x8 Af = *(const u16x8*)&Wt[i * 1024 + lane * 8];
            u16x8 Bf = *(const u16x8*)&Wt[i * 1024 + 512 + lane * 8];
            f32x4 c = {0.f,0.f,0.f,0.f};
            c = __builtin_amdgcn_mfma_f32_16x16x32_bf16(__builtin_bit_cast(bf16x8, Af), HB0, c, 0, 0, 0);
            c = __builtin_amdgcn_mfma_f32_16x16x32_bf16(__builtin_bit_cast(bf16x8, Bf), HB1, c, 0, 0, 0);
            if (i < 2) {
                int j = i*4 + quad;
                #pragma unroll
                for (int i3 = 0; i3 < 3; i3++) {
                    float f = Fp[j*3 + i3];
                    #pragma unroll
                    for (int r = 0; r < 4; r++) t1[i3*4 + r] += f * c[r];
                }
            } else if (i < 6) {
                float f = Fp[24 + (i - 2)*4 + quad];
                #pragma unroll
                for (int r = 0; r < 4; r++) sD[r] += f * c[r];
            } else {
                float f = Fp[40 + (i - 6)];
                #pragma unroll
                for (int r = 0; r < 4; r++) oo[r] += f * c[r];
            }
        }
        #pragma unroll
        for (int r = 0; r < 4; r++) {
            sD[r] += __shfl_xor(sD[r], 16, 64);  sD[r] += __shfl_xor(sD[r], 32, 64);
        }
        #pragma unroll
        for (int i = 0; i < 12; i++) {
            t1[i] += __shfl_xor(t1[i], 16, 64);  t1[i] += __shfl_xor(t1[i], 32, 64);
        }
        float4 v1; v1.x = oo[0]; v1.y = oo[1]; v1.z = oo[2]; v1.w = oo[3];
        *(float4*)&sO[em * IRR + 28 + 12 + quad*4] = v1;      // ch 40..55
        if (quad == 0) {
            #pragma unroll
            for (int r = 0; r < 4; r++) {                     // ch 28..39
                sO[em * IRR + 28 + r*3 + 0] = sD[r] * sx + t1[0*4 + r];
                sO[em * IRR + 28 + r*3 + 1] = sD[r] * sy + t1[1*4 + r];
                sO[em * IRR + 28 + r*3 + 2] = sD[r] * sz + t1[2*4 + r];
            }
        }
    }

    __syncthreads();   // (E) sO complete block-wide

    // ---- pre-scaled atomic scatter: full contiguous 224 B rows per edge ----
    #pragma unroll
    for (int it = 0; it < 7; it++) {
        int idx = it * NT + tid;           // < 3584 = 64*56
        int e = idx / IRR, ch = idx - e * IRR;
        unsafeAtomicAdd(&out[(size_t)sSrc[e] * IRR + ch], sO[e * IRR + ch] * sInv[e]);
    }
}

extern "C" void kernel_launch(void* const* d_in, const int* in_sizes, int n_in,
                              void* d_out, int out_size, void* d_ws, size_t ws_size,
                              hipStream_t stream) {
    const float* node_attr  = (const float*)d_in[0];
    const float* edge_attr  = (const float*)d_in[1];
    const float* edge_sh    = (const float*)d_in[2];
    const float* fc_w1      = (const float*)d_in[3];
    const float* fc_b1      = (const float*)d_in[4];
    const float* fc_w2      = (const float*)d_in[5];
    const float* fc_b2      = (const float*)d_in[6];
    const int*   edge_index = (const int*)d_in[7];

    int* hist = (int*)d_ws;                                    // 8000 ints
    unsigned short* W1T = (unsigned short*)(hist + NNODE);     // 48*64
    unsigned short* W2L = W1T + EF * 64;                       // 52*2*64*8 = 53248

    hipMemsetAsync(hist, 0, NNODE * sizeof(int), stream);
    hipMemsetAsync(d_out, 0, (size_t)out_size * sizeof(float), stream);

    k_setup<<<(NEDGE + 255) / 256, 256, 0, stream>>>(
        fc_w1, fc_b1, fc_w2, fc_b2, W1T, W2L, edge_index, hist);

    tp_fused<<<GRID, NT, 0, stream>>>(node_attr, edge_attr, edge_sh, edge_index,
                                      hist, W1T, W2L, (float*)d_out);
}